// Round 1
// baseline (3991.982 us; speedup 1.0000x reference)
//
#include <hip/hip_runtime.h>
#include <hip/hip_bf16.h>

#define B_ 32
#define L_ 256
#define W_ 32
#define DEPTH_ 4
#define TILE 16
#define HALO 18
#define LL (L_*L_)

__device__ __forceinline__ float gelu_exact(float v) {
    return 0.5f * v * (1.0f + erff(v * 0.70710678118654752f));
}

__device__ __forceinline__ float ld_val(const float* p, size_t idx) { return p[idx]; }
__device__ __forceinline__ float ld_val(const __hip_bfloat16* p, size_t idx) { return __bfloat162float(p[idx]); }
__device__ __forceinline__ void st_val(float* p, size_t idx, float v) { p[idx] = v; }
__device__ __forceinline__ void st_val(__hip_bfloat16* p, size_t idx, float v) { p[idx] = __float2bfloat16(v); }

// ---------------- first layer: 1 channel -> 32 channels ----------------
template<typename T>
__global__ __launch_bounds__(256) void kern_first(
        const float* __restrict__ x, float scale,
        const float* __restrict__ ci, const float* __restrict__ bi,
        const float* __restrict__ ai, const float* __restrict__ bias_i,
        T* __restrict__ hout) {
    __shared__ float tile[HALO*HALO];
    __shared__ float wC[W_], wB[W_], wA[W_], bs[W_];
    int blk = blockIdx.x;
    int b = blk >> 8;
    int t = blk & 255;
    int x0 = (t >> 4) * TILE;
    int y0 = (t & 15) * TILE;
    int tid = threadIdx.x;
    if (tid < W_) { wC[tid] = ci[tid]; wB[tid] = bi[tid]; wA[tid] = ai[tid]; bs[tid] = bias_i[tid]; }
    const float* xb = x + (size_t)b * LL;
    for (int idx = tid; idx < HALO*HALO; idx += 256) {
        int dy = idx / HALO, dx = idx % HALO;
        int gx = (x0 + dy - 1) & (L_ - 1);
        int gy = (y0 + dx - 1) & (L_ - 1);
        tile[idx] = scale * xb[gx * L_ + gy];
    }
    __syncthreads();
    int dx = tid & 15, dy = tid >> 4;
    const float* c0 = &tile[dy * HALO + dx];
    float ctr = c0[HALO + 1];
    float nb  = c0[1] + c0[2*HALO+1] + c0[HALO] + c0[HALO+2];
    float dg  = c0[0] + c0[2] + c0[2*HALO] + c0[2*HALO+2];
    size_t base = (size_t)b * W_ * LL + (size_t)(x0+dy) * L_ + (y0+dx);
    #pragma unroll
    for (int o = 0; o < W_; ++o) {
        float y = wC[o]*ctr + wB[o]*nb + wA[o]*dg + bs[o];
        st_val(hout, base + (size_t)o * LL, gelu_exact(y));
    }
}

// ---------------- middle layer: 32 -> 32 channels ----------------
template<typename T>
__global__ __launch_bounds__(256) void kern_mid(
        const T* __restrict__ hin,
        const float* __restrict__ wc, const float* __restrict__ wb,
        const float* __restrict__ wa, const float* __restrict__ bias,
        T* __restrict__ hout) {
    __shared__ float tile[W_][HALO*HALO];   // 41472 B
    int blk = blockIdx.x;
    int b = blk >> 8;
    int t = blk & 255;
    int x0 = (t >> 4) * TILE;
    int y0 = (t & 15) * TILE;
    int tid = threadIdx.x;
    const T* hb = hin + (size_t)b * W_ * LL;
    for (int idx = tid; idx < W_*HALO*HALO; idx += 256) {
        int i = idx / (HALO*HALO);
        int r = idx % (HALO*HALO);
        int dy = r / HALO, dx = r % HALO;
        int gx = (x0 + dy - 1) & (L_ - 1);
        int gy = (y0 + dx - 1) & (L_ - 1);
        tile[i][r] = ld_val(hb, (size_t)i * LL + gx * L_ + gy);
    }
    __syncthreads();
    int dx = tid & 15, dy = tid >> 4;
    float acc[W_];
    #pragma unroll
    for (int o = 0; o < W_; ++o) acc[o] = bias[o];
    for (int i = 0; i < W_; ++i) {
        const float* c0 = &tile[i][dy * HALO + dx];
        float ctr = c0[HALO + 1];
        float nb  = c0[1] + c0[2*HALO+1] + c0[HALO] + c0[HALO+2];
        float dg  = c0[0] + c0[2] + c0[2*HALO] + c0[2*HALO+2];
        #pragma unroll
        for (int o = 0; o < W_; ++o) {
            // lane-uniform indices -> scalar loads, dual-issue with VALU
            acc[o] += wc[o*W_+i]*ctr + wb[o*W_+i]*nb + wa[o*W_+i]*dg;
        }
    }
    size_t base = (size_t)b * W_ * LL + (size_t)(x0+dy) * L_ + (y0+dx);
    #pragma unroll
    for (int o = 0; o < W_; ++o)
        st_val(hout, base + (size_t)o * LL, gelu_exact(acc[o]));
}

// ---------------- last layer: 32 -> 1 channel, antisym accumulate ----------------
template<typename T>
__global__ __launch_bounds__(256) void kern_last(
        const T* __restrict__ hin,
        const float* __restrict__ co, const float* __restrict__ bo,
        const float* __restrict__ ao,
        float* __restrict__ out, int mode) {
    __shared__ float tile[W_][HALO*HALO];
    int blk = blockIdx.x;
    int b = blk >> 8;
    int t = blk & 255;
    int x0 = (t >> 4) * TILE;
    int y0 = (t & 15) * TILE;
    int tid = threadIdx.x;
    const T* hb = hin + (size_t)b * W_ * LL;
    for (int idx = tid; idx < W_*HALO*HALO; idx += 256) {
        int i = idx / (HALO*HALO);
        int r = idx % (HALO*HALO);
        int dy = r / HALO, dx = r % HALO;
        int gx = (x0 + dy - 1) & (L_ - 1);
        int gy = (y0 + dx - 1) & (L_ - 1);
        tile[i][r] = ld_val(hb, (size_t)i * LL + gx * L_ + gy);
    }
    __syncthreads();
    int dx = tid & 15, dy = tid >> 4;
    float acc = 0.0f;
    for (int i = 0; i < W_; ++i) {
        const float* c0 = &tile[i][dy * HALO + dx];
        float ctr = c0[HALO + 1];
        float nb  = c0[1] + c0[2*HALO+1] + c0[HALO] + c0[HALO+2];
        float dg  = c0[0] + c0[2] + c0[2*HALO] + c0[2*HALO+2];
        acc += co[i]*ctr + bo[i]*nb + ao[i]*dg;
    }
    size_t oidx = (size_t)b * LL + (size_t)(x0+dy) * L_ + (y0+dx);
    if (mode == 0) out[oidx] = 0.5f * acc;
    else           out[oidx] = out[oidx] - 0.5f * acc;
}

template<typename T>
static void run_pipeline(const float* x, const float* ai, const float* ao, const float* a,
                         const float* bi, const float* bo, const float* b,
                         const float* ci, const float* co, const float* c,
                         const float* bias_i, const float* bias,
                         float* out, T* hA, T* hB, hipStream_t stream) {
    dim3 grid(B_ * 256), blk(256);
    for (int s = 0; s < 2; ++s) {
        float scale = s ? -1.0f : 1.0f;
        kern_first<T><<<grid, blk, 0, stream>>>(x, scale, ci, bi, ai, bias_i, hA);
        T* cur = hA; T* nxt = hB;
        for (int k = 0; k < DEPTH_; ++k) {
            kern_mid<T><<<grid, blk, 0, stream>>>(cur, c + k*W_*W_, b + k*W_*W_, a + k*W_*W_,
                                                  bias + k*W_, nxt);
            T* tmp = cur; cur = nxt; nxt = tmp;
        }
        kern_last<T><<<grid, blk, 0, stream>>>(cur, co, bo, ao, out, s);
    }
}

extern "C" void kernel_launch(void* const* d_in, const int* in_sizes, int n_in,
                              void* d_out, int out_size, void* d_ws, size_t ws_size,
                              hipStream_t stream) {
    const float* x      = (const float*)d_in[0];
    const float* ai     = (const float*)d_in[1];
    const float* ao     = (const float*)d_in[2];
    const float* a      = (const float*)d_in[3];
    const float* bi     = (const float*)d_in[4];
    const float* bo     = (const float*)d_in[5];
    const float* b      = (const float*)d_in[6];
    const float* ci     = (const float*)d_in[7];
    const float* co     = (const float*)d_in[8];
    const float* c      = (const float*)d_in[9];
    const float* bias_i = (const float*)d_in[10];
    const float* bias   = (const float*)d_in[11];
    float* out = (float*)d_out;

    const size_t elems = (size_t)B_ * W_ * LL;   // 67,108,864
    if (ws_size >= 2 * elems * sizeof(float)) {
        float* hA = (float*)d_ws;
        float* hB = hA + elems;
        run_pipeline<float>(x, ai, ao, a, bi, bo, b, ci, co, c, bias_i, bias, out, hA, hB, stream);
    } else {
        __hip_bfloat16* hA = (__hip_bfloat16*)d_ws;
        __hip_bfloat16* hB = hA + elems;
        run_pipeline<__hip_bfloat16>(x, ai, ao, a, bi, bo, b, ci, co, c, bias_i, bias, out, hA, hB, stream);
    }
}

// Round 2
// 2491.009 us; speedup vs baseline: 1.6026x; 1.6026x over previous
//
#include <hip/hip_runtime.h>
#include <hip/hip_bf16.h>

#define B_ 32
#define L_ 256
#define W_ 32
#define DEPTH_ 4
#define TILE 16
#define HALO 18
#define TPAD 20          // padded tile row stride (floats) -> float4-aligned windows
#define FPAD 36          // padded feature channel stride (shorts) -> b64-aligned, bank-spread
#define LL (L_*L_)

typedef float  floatx4 __attribute__((ext_vector_type(4)));
typedef float  floatx2 __attribute__((ext_vector_type(2)));
typedef short  shortx4 __attribute__((ext_vector_type(4)));
typedef short  shortx8 __attribute__((ext_vector_type(8)));

__device__ __forceinline__ float gelu_exact(float v) {
    return 0.5f * v * (1.0f + erff(v * 0.70710678118654752f));
}
__device__ __forceinline__ unsigned short f2bf(float v) {
    __hip_bfloat16 h = __float2bfloat16(v);
    return __builtin_bit_cast(unsigned short, h);
}
__device__ __forceinline__ float bf2f(unsigned short u) {
    __hip_bfloat16 h = __builtin_bit_cast(__hip_bfloat16, u);
    return __bfloat162float(h);
}

// ---------------- first layer: 1 channel -> 32 channels ----------------
__global__ __launch_bounds__(256) void kern_first(
        const float* __restrict__ x, float scale,
        const float* __restrict__ ci, const float* __restrict__ bi,
        const float* __restrict__ ai, const float* __restrict__ bias_i,
        __hip_bfloat16* __restrict__ hout) {
    __shared__ float tile[HALO*HALO];
    __shared__ float wC[W_], wB[W_], wA[W_], bs[W_];
    int blk = blockIdx.x;
    int b = blk >> 8;
    int t = blk & 255;
    int x0 = (t >> 4) * TILE;
    int y0 = (t & 15) * TILE;
    int tid = threadIdx.x;
    if (tid < W_) { wC[tid] = ci[tid]; wB[tid] = bi[tid]; wA[tid] = ai[tid]; bs[tid] = bias_i[tid]; }
    const float* xb = x + (size_t)b * LL;
    for (int idx = tid; idx < HALO*HALO; idx += 256) {
        int dy = idx / HALO, dx = idx % HALO;
        int gx = (x0 + dy - 1) & (L_ - 1);
        int gy = (y0 + dx - 1) & (L_ - 1);
        tile[idx] = scale * xb[gx * L_ + gy];
    }
    __syncthreads();
    int dx = tid & 15, dy = tid >> 4;
    const float* c0 = &tile[dy * HALO + dx];
    float ctr = c0[HALO + 1];
    float nb  = c0[1] + c0[2*HALO+1] + c0[HALO] + c0[HALO+2];
    float dg  = c0[0] + c0[2] + c0[2*HALO] + c0[2*HALO+2];
    size_t base = (size_t)b * W_ * LL + (size_t)(x0+dy) * L_ + (y0+dx);
    #pragma unroll
    for (int o = 0; o < W_; ++o) {
        float y = wC[o]*ctr + wB[o]*nb + wA[o]*dg + bs[o];
        hout[base + (size_t)o * LL] = __float2bfloat16(gelu_exact(y));
    }
}

// ---------------- middle layer: 32 -> 32 channels, MFMA ----------------
__global__ __launch_bounds__(256) void kern_mid(
        const __hip_bfloat16* __restrict__ hin,
        const float* __restrict__ wc, const float* __restrict__ wb,
        const float* __restrict__ wa, const float* __restrict__ bias,
        __hip_bfloat16* __restrict__ hout) {
    __shared__ float tile[W_ * HALO * TPAD];         // 46080 B
    __shared__ unsigned short feat[3 * 64 * FPAD];   // 13824 B  (total 59904 <= 64K)

    const int tid = threadIdx.x;
    const int blk = blockIdx.x;
    const int b  = blk >> 8;
    const int t  = blk & 255;
    const int x0 = (t >> 4) * TILE;
    const int y0 = (t & 15) * TILE;

    // ---- stage input tile as fp32 (padded rows) ----
    const __hip_bfloat16* hb = hin + (size_t)b * W_ * LL;
    for (int idx = tid; idx < W_ * HALO * HALO; idx += 256) {
        int i  = idx / (HALO*HALO);
        int r  = idx - i * (HALO*HALO);
        int dy = r / HALO;
        int dx = r - dy * HALO;
        int gx = (x0 + dy - 1) & (L_ - 1);
        int gy = (y0 + dx - 1) & (L_ - 1);
        tile[i * (HALO*TPAD) + dy * TPAD + dx] =
            __bfloat162float(hb[(size_t)i * LL + gx * L_ + gy]);
    }

    // ---- A fragments (weights bf16 hi/lo) + bias, built once ----
    const int lane = tid & 63;
    const int wv   = tid >> 6;       // wave 0..3
    const int m    = lane & 15;      // site-col / out-row-within-half selector
    const int q    = lane >> 4;      // k-quad
    const float* wmat[3] = { wc, wb, wa };
    shortx8 afrag[3][2][2];          // [mat][half][hi/lo]
    #pragma unroll
    for (int f = 0; f < 3; ++f)
      #pragma unroll
      for (int h = 0; h < 2; ++h) {
        const float* row = wmat[f] + (h*16 + m) * W_ + q*8;
        shortx8 hi, lo;
        #pragma unroll
        for (int j = 0; j < 8; ++j) {
            float v = row[j];
            unsigned short hb16 = f2bf(v);
            hi[j] = (short)hb16;
            lo[j] = (short)f2bf(v - bf2f(hb16));
        }
        afrag[f][h][0] = hi;
        afrag[f][h][1] = lo;
      }
    float bias_v[2][4];
    #pragma unroll
    for (int h = 0; h < 2; ++h)
      #pragma unroll
      for (int r = 0; r < 4; ++r)
        bias_v[h][r] = bias[h*16 + q*4 + r];

    __syncthreads();

    // ---- 4 phases of 4 site-rows (64 sites) each ----
    for (int p = 0; p < 4; ++p) {
        // features: 64 sites x 32 ch = 512 four-site segments -> 2 per thread
        #pragma unroll
        for (int ss = 0; ss < 2; ++ss) {
            int seg = tid + ss * 256;
            int i   = seg & 31;          // channel
            int sp  = seg >> 5;          // 0..15 spatial segment
            int rr  = sp >> 2;           // row 0..3 within phase
            int qy  = sp & 3;            // y-quad
            const float* base = &tile[i*(HALO*TPAD) + (p*4+rr)*TPAD + qy*4];
            float u[6], c[6], d[6];
            *(floatx4*)(u)   = *(const floatx4*)(base);
            *(floatx2*)(u+4) = *(const floatx2*)(base+4);
            *(floatx4*)(c)   = *(const floatx4*)(base+TPAD);
            *(floatx2*)(c+4) = *(const floatx2*)(base+TPAD+4);
            *(floatx4*)(d)   = *(const floatx4*)(base+2*TPAD);
            *(floatx2*)(d+4) = *(const floatx2*)(base+2*TPAD+4);
            int sbase = rr*16 + qy*4;
            #pragma unroll
            for (int j = 0; j < 4; ++j) {
                float ctr = c[j+1];
                float nb  = u[j+1] + d[j+1] + c[j] + c[j+2];
                float dg  = u[j] + u[j+2] + d[j] + d[j+2];
                int s = sbase + j;
                feat[(0*64 + s)*FPAD + i] = f2bf(ctr);
                feat[(1*64 + s)*FPAD + i] = f2bf(nb);
                feat[(2*64 + s)*FPAD + i] = f2bf(dg);
            }
        }
        __syncthreads();

        // MFMA: wave wv handles site-row wv; sites s = wv*16 + m
        int s = wv*16 + m;
        floatx4 acc[2] = {{0.f,0.f,0.f,0.f},{0.f,0.f,0.f,0.f}};
        #pragma unroll
        for (int f = 0; f < 3; ++f) {
            const unsigned short* fb = &feat[(f*64 + s)*FPAD + q*8];
            union { shortx8 v8; shortx4 v4[2]; } uu;
            uu.v4[0] = *(const shortx4*)(fb);
            uu.v4[1] = *(const shortx4*)(fb+4);
            #pragma unroll
            for (int h = 0; h < 2; ++h) {
                acc[h] = __builtin_amdgcn_mfma_f32_16x16x32_bf16(afrag[f][h][1], uu.v8, acc[h], 0, 0, 0);
                acc[h] = __builtin_amdgcn_mfma_f32_16x16x32_bf16(afrag[f][h][0], uu.v8, acc[h], 0, 0, 0);
            }
        }
        __syncthreads();   // feat reused next phase

        // epilogue: C/D layout col=lane&15 (site y), row=q*4+r (out within half)
        int gx = x0 + p*4 + wv;
        int gy = y0 + m;
        #pragma unroll
        for (int h = 0; h < 2; ++h)
          #pragma unroll
          for (int r = 0; r < 4; ++r) {
            int oc = h*16 + q*4 + r;
            float v = gelu_exact(acc[h][r] + bias_v[h][r]);
            hout[((size_t)b*W_ + oc)*LL + (size_t)gx*L_ + gy] = __float2bfloat16(v);
          }
    }
}

// ---------------- last layer: 32 -> 1 channel, antisym accumulate ----------------
__global__ __launch_bounds__(256) void kern_last(
        const __hip_bfloat16* __restrict__ hin,
        const float* __restrict__ co, const float* __restrict__ bo,
        const float* __restrict__ ao,
        float* __restrict__ out, int mode) {
    __shared__ float tile[W_][HALO*HALO];
    int blk = blockIdx.x;
    int b = blk >> 8;
    int t = blk & 255;
    int x0 = (t >> 4) * TILE;
    int y0 = (t & 15) * TILE;
    int tid = threadIdx.x;
    const __hip_bfloat16* hb = hin + (size_t)b * W_ * LL;
    for (int idx = tid; idx < W_*HALO*HALO; idx += 256) {
        int i = idx / (HALO*HALO);
        int r = idx % (HALO*HALO);
        int dy = r / HALO, dx = r % HALO;
        int gx = (x0 + dy - 1) & (L_ - 1);
        int gy = (y0 + dx - 1) & (L_ - 1);
        tile[i][r] = __bfloat162float(hb[(size_t)i * LL + gx * L_ + gy]);
    }
    __syncthreads();
    int dx = tid & 15, dy = tid >> 4;
    float acc = 0.0f;
    for (int i = 0; i < W_; ++i) {
        const float* c0 = &tile[i][dy * HALO + dx];
        float ctr = c0[HALO + 1];
        float nb  = c0[1] + c0[2*HALO+1] + c0[HALO] + c0[HALO+2];
        float dg  = c0[0] + c0[2] + c0[2*HALO] + c0[2*HALO+2];
        acc += co[i]*ctr + bo[i]*nb + ao[i]*dg;
    }
    size_t oidx = (size_t)b * LL + (size_t)(x0+dy) * L_ + (y0+dx);
    if (mode == 0) out[oidx] = 0.5f * acc;
    else           out[oidx] = out[oidx] - 0.5f * acc;
}

extern "C" void kernel_launch(void* const* d_in, const int* in_sizes, int n_in,
                              void* d_out, int out_size, void* d_ws, size_t ws_size,
                              hipStream_t stream) {
    const float* x      = (const float*)d_in[0];
    const float* ai     = (const float*)d_in[1];
    const float* ao     = (const float*)d_in[2];
    const float* a      = (const float*)d_in[3];
    const float* bi     = (const float*)d_in[4];
    const float* bo     = (const float*)d_in[5];
    const float* b      = (const float*)d_in[6];
    const float* ci     = (const float*)d_in[7];
    const float* co     = (const float*)d_in[8];
    const float* c      = (const float*)d_in[9];
    const float* bias_i = (const float*)d_in[10];
    const float* bias   = (const float*)d_in[11];
    float* out = (float*)d_out;

    const size_t elems = (size_t)B_ * W_ * LL;
    __hip_bfloat16* hA = (__hip_bfloat16*)d_ws;
    __hip_bfloat16* hB = hA + elems;

    dim3 grid(B_ * 256), blk(256);
    for (int s = 0; s < 2; ++s) {
        float scale = s ? -1.0f : 1.0f;
        kern_first<<<grid, blk, 0, stream>>>(x, scale, ci, bi, ai, bias_i, hA);
        __hip_bfloat16* cur = hA; __hip_bfloat16* nxt = hB;
        for (int k = 0; k < DEPTH_; ++k) {
            kern_mid<<<grid, blk, 0, stream>>>(cur, c + k*W_*W_, b + k*W_*W_, a + k*W_*W_,
                                               bias + k*W_, nxt);
            __hip_bfloat16* tmp = cur; cur = nxt; nxt = tmp;
        }
        kern_last<<<grid, blk, 0, stream>>>(cur, co, bo, ao, out, s);
    }
}

// Round 3
// 1406.059 us; speedup vs baseline: 2.8391x; 1.7716x over previous
//
#include <hip/hip_runtime.h>
#include <hip/hip_bf16.h>

#define B_ 32
#define L_ 256
#define W_ 32
#define DEPTH_ 4
#define TILE 16
#define HALO 18
#define FPAD 36          // feature channel stride (shorts): 72B, 8B-aligned for b64 frags
#define RSTRIDE 20       // tile row stride in shorts: [pad][lh][main0..15][rh][pad]
#define CSTRIDE 362      // tile channel stride in shorts = 181 words (odd -> bank-spread)
#define LL (L_*L_)

typedef float  floatx4 __attribute__((ext_vector_type(4)));
typedef short  shortx2 __attribute__((ext_vector_type(2)));
typedef short  shortx4 __attribute__((ext_vector_type(4)));
typedef short  shortx8 __attribute__((ext_vector_type(8)));

__device__ __forceinline__ float gelu_exact(float v) {
    return 0.5f * v * (1.0f + erff(v * 0.70710678118654752f));
}
__device__ __forceinline__ unsigned short f2bf(float v) {
    __hip_bfloat16 h = __float2bfloat16(v);
    return __builtin_bit_cast(unsigned short, h);
}
__device__ __forceinline__ float bf2f(unsigned short u) {
    __hip_bfloat16 h = __builtin_bit_cast(__hip_bfloat16, u);
    return __bfloat162float(h);
}
__device__ __forceinline__ float hi16(unsigned r) { return __uint_as_float(r & 0xffff0000u); }
__device__ __forceinline__ float lo16(unsigned r) { return __uint_as_float(r << 16); }

// window shorts e..e+7 in r0..r3; logical window = shorts e+1..e+6
__device__ __forceinline__ void unpack6(unsigned r0, unsigned r1, unsigned r2, unsigned r3, float* w) {
    w[0] = hi16(r0);
    w[1] = lo16(r1); w[2] = hi16(r1);
    w[3] = lo16(r2); w[4] = hi16(r2);
    w[5] = lo16(r3);
}

// XCD-aware swizzle: HW assigns XCD = dispatch_index % 8. Give each XCD a
// contiguous logical range so y-adjacent tiles (sharing 128B lines) stay in one L2.
__device__ __forceinline__ int swizzle_blk(int p) {
    return (p & 7) * 1024 + (p >> 3);
}

// ---------------- first layer: 1 channel -> 32 channels ----------------
__global__ __launch_bounds__(256) void kern_first(
        const float* __restrict__ x, float scale,
        const float* __restrict__ ci, const float* __restrict__ bi,
        const float* __restrict__ ai, const float* __restrict__ bias_i,
        __hip_bfloat16* __restrict__ hout) {
    __shared__ float tile[HALO*HALO];
    __shared__ float wC[W_], wB[W_], wA[W_], bs[W_];
    int blk = swizzle_blk(blockIdx.x);
    int b = blk >> 8;
    int t = blk & 255;
    int x0 = (t >> 4) * TILE;
    int y0 = (t & 15) * TILE;
    int tid = threadIdx.x;
    if (tid < W_) { wC[tid] = ci[tid]; wB[tid] = bi[tid]; wA[tid] = ai[tid]; bs[tid] = bias_i[tid]; }
    const float* xb = x + (size_t)b * LL;
    for (int idx = tid; idx < HALO*HALO; idx += 256) {
        int dy = idx / HALO, dx = idx % HALO;
        int gx = (x0 + dy - 1) & (L_ - 1);
        int gy = (y0 + dx - 1) & (L_ - 1);
        tile[idx] = scale * xb[gx * L_ + gy];
    }
    __syncthreads();
    int dx = tid & 15, dy = tid >> 4;
    const float* c0 = &tile[dy * HALO + dx];
    float ctr = c0[HALO + 1];
    float nb  = c0[1] + c0[2*HALO+1] + c0[HALO] + c0[HALO+2];
    float dg  = c0[0] + c0[2] + c0[2*HALO] + c0[2*HALO+2];
    size_t base = (size_t)b * W_ * LL + (size_t)(x0+dy) * L_ + (y0+dx);
    #pragma unroll
    for (int o = 0; o < W_; ++o) {
        float y = wC[o]*ctr + wB[o]*nb + wA[o]*dg + bs[o];
        hout[base + (size_t)o * LL] = __float2bfloat16(gelu_exact(y));
    }
}

// ---------------- middle layer staging helper ----------------
__device__ __forceinline__ void stage_row(unsigned short* tile_s, const unsigned short* hb,
                                          int j, int x0, int y0) {
    int i  = j & 31;
    int dy = j >> 5;
    int gx = (x0 + dy - 1) & (L_ - 1);
    const unsigned short* src = hb + (size_t)i * LL + (size_t)gx * L_;
    shortx8 m0 = *(const shortx8*)(src + y0);        // 16B, 32B-aligned
    shortx8 m1 = *(const shortx8*)(src + y0 + 8);
    unsigned short lh = src[(y0 - 1) & (L_ - 1)];
    unsigned short rh = src[(y0 + 16) & (L_ - 1)];
    unsigned short* dst = tile_s + i * CSTRIDE + dy * RSTRIDE;
    shortx2* dp = (shortx2*)(dst + 2);               // main at idx 2..17 (4B-aligned pairs)
    const shortx2* p0 = (const shortx2*)&m0;
    const shortx2* p1 = (const shortx2*)&m1;
    dp[0] = p0[0]; dp[1] = p0[1]; dp[2] = p0[2]; dp[3] = p0[3];
    dp[4] = p1[0]; dp[5] = p1[1]; dp[6] = p1[2]; dp[7] = p1[3];
    dst[1]  = lh;                                    // logical col -1
    dst[18] = rh;                                    // logical col 16
}

// ---------------- middle layer: 32 -> 32 channels, MFMA ----------------
__global__ __launch_bounds__(256, 4) void kern_mid(
        const __hip_bfloat16* __restrict__ hin,
        const float* __restrict__ wc, const float* __restrict__ wb,
        const float* __restrict__ wa, const float* __restrict__ bias,
        __hip_bfloat16* __restrict__ hout) {
    __shared__ unsigned short tile_s[W_ * CSTRIDE];      // 23168 B, bf16
    __shared__ unsigned short feat[3 * 64 * FPAD];       // 13824 B   (total 36992 -> 4 blocks/CU)

    const int tid = threadIdx.x;
    const int blk = swizzle_blk(blockIdx.x);
    const int b  = blk >> 8;
    const int t  = blk & 255;
    const int x0 = (t >> 4) * TILE;
    const int y0 = (t & 15) * TILE;

    const unsigned short* hb = (const unsigned short*)hin + (size_t)b * W_ * LL;

    // ---- stage input tile (bf16, padded rows): 576 row-jobs of 18 elems ----
    stage_row(tile_s, hb, tid,       x0, y0);
    stage_row(tile_s, hb, tid + 256, x0, y0);
    if (tid < 64) stage_row(tile_s, hb, tid + 512, x0, y0);

    // ---- A fragments (weights bf16 hi/lo) + bias, built once ----
    const int lane = tid & 63;
    const int wv   = tid >> 6;       // wave 0..3
    const int m    = lane & 15;
    const int q    = lane >> 4;      // k-quad
    const float* wmat[3] = { wc, wb, wa };
    shortx8 afrag[3][2][2];          // [mat][half][hi/lo]
    #pragma unroll
    for (int f = 0; f < 3; ++f)
      #pragma unroll
      for (int h = 0; h < 2; ++h) {
        const float* row = wmat[f] + (h*16 + m) * W_ + q*8;
        shortx8 hi, lo;
        #pragma unroll
        for (int j = 0; j < 8; ++j) {
            float v = row[j];
            unsigned short hb16 = f2bf(v);
            hi[j] = (short)hb16;
            lo[j] = (short)f2bf(v - bf2f(hb16));
        }
        afrag[f][h][0] = hi;
        afrag[f][h][1] = lo;
      }
    float bias_v[2][4];
    #pragma unroll
    for (int h = 0; h < 2; ++h)
      #pragma unroll
      for (int r = 0; r < 4; ++r)
        bias_v[h][r] = bias[h*16 + q*4 + r];

    __syncthreads();

    const unsigned* tw = (const unsigned*)tile_s;    // word view (channel stride 181, odd)

    // ---- 4 phases of 4 site-rows (64 sites) each ----
    for (int p = 0; p < 4; ++p) {
        #pragma unroll
        for (int ss = 0; ss < 2; ++ss) {
            int seg = tid + ss * 256;
            int i   = seg & 31;          // channel
            int sp  = seg >> 5;          // 0..15
            int rr  = sp >> 2;           // row within phase
            int qy  = sp & 3;            // y-quad
            int wbw = i * 181 + (p*4 + rr) * 10 + qy * 2;
            float u[6], c[6], d[6];
            unpack6(tw[wbw],    tw[wbw+1],  tw[wbw+2],  tw[wbw+3],  u);
            unpack6(tw[wbw+10], tw[wbw+11], tw[wbw+12], tw[wbw+13], c);
            unpack6(tw[wbw+20], tw[wbw+21], tw[wbw+22], tw[wbw+23], d);
            int sbase = rr*16 + qy*4;
            #pragma unroll
            for (int j = 0; j < 4; ++j) {
                float ctr = c[j+1];
                float nb  = u[j+1] + d[j+1] + c[j] + c[j+2];
                float dg  = u[j] + u[j+2] + d[j] + d[j+2];
                int s = sbase + j;
                feat[(0*64 + s)*FPAD + i] = f2bf(ctr);
                feat[(1*64 + s)*FPAD + i] = f2bf(nb);
                feat[(2*64 + s)*FPAD + i] = f2bf(dg);
            }
        }
        __syncthreads();

        // MFMA: wave wv handles site-row wv; sites s = wv*16 + m
        int s = wv*16 + m;
        floatx4 acc[2] = {{0.f,0.f,0.f,0.f},{0.f,0.f,0.f,0.f}};
        #pragma unroll
        for (int f = 0; f < 3; ++f) {
            const unsigned short* fb = &feat[(f*64 + s)*FPAD + q*8];
            union { shortx8 v8; shortx4 v4[2]; } uu;
            uu.v4[0] = *(const shortx4*)(fb);
            uu.v4[1] = *(const shortx4*)(fb+4);
            #pragma unroll
            for (int h = 0; h < 2; ++h) {
                acc[h] = __builtin_amdgcn_mfma_f32_16x16x32_bf16(afrag[f][h][1], uu.v8, acc[h], 0, 0, 0);
                acc[h] = __builtin_amdgcn_mfma_f32_16x16x32_bf16(afrag[f][h][0], uu.v8, acc[h], 0, 0, 0);
            }
        }
        __syncthreads();   // feat reused next phase

        // epilogue: C/D layout col=lane&15 (site y), row=q*4+r (out within half)
        int gx = x0 + p*4 + wv;
        int gy = y0 + m;
        #pragma unroll
        for (int h = 0; h < 2; ++h)
          #pragma unroll
          for (int r = 0; r < 4; ++r) {
            int oc = h*16 + q*4 + r;
            float v = gelu_exact(acc[h][r] + bias_v[h][r]);
            hout[((size_t)b*W_ + oc)*LL + (size_t)gx*L_ + gy] = __float2bfloat16(v);
          }
    }
}

// ---------------- last layer: 32 -> 1 channel, antisym accumulate ----------------
__global__ __launch_bounds__(256) void kern_last(
        const __hip_bfloat16* __restrict__ hin,
        const float* __restrict__ co, const float* __restrict__ bo,
        const float* __restrict__ ao,
        float* __restrict__ out, int mode) {
    __shared__ float tile[W_][HALO*HALO];
    int blk = swizzle_blk(blockIdx.x);
    int b = blk >> 8;
    int t = blk & 255;
    int x0 = (t >> 4) * TILE;
    int y0 = (t & 15) * TILE;
    int tid = threadIdx.x;
    const __hip_bfloat16* hb = hin + (size_t)b * W_ * LL;
    for (int idx = tid; idx < W_*HALO*HALO; idx += 256) {
        int i = idx / (HALO*HALO);
        int r = idx % (HALO*HALO);
        int dy = r / HALO, dx = r % HALO;
        int gx = (x0 + dy - 1) & (L_ - 1);
        int gy = (y0 + dx - 1) & (L_ - 1);
        tile[i][r] = __bfloat162float(hb[(size_t)i * LL + gx * L_ + gy]);
    }
    __syncthreads();
    int dx = tid & 15, dy = tid >> 4;
    float acc = 0.0f;
    for (int i = 0; i < W_; ++i) {
        const float* c0 = &tile[i][dy * HALO + dx];
        float ctr = c0[HALO + 1];
        float nb  = c0[1] + c0[2*HALO+1] + c0[HALO] + c0[HALO+2];
        float dg  = c0[0] + c0[2] + c0[2*HALO] + c0[2*HALO+2];
        acc += co[i]*ctr + bo[i]*nb + ao[i]*dg;
    }
    size_t oidx = (size_t)b * LL + (size_t)(x0+dy) * L_ + (y0+dx);
    if (mode == 0) out[oidx] = 0.5f * acc;
    else           out[oidx] = out[oidx] - 0.5f * acc;
}

extern "C" void kernel_launch(void* const* d_in, const int* in_sizes, int n_in,
                              void* d_out, int out_size, void* d_ws, size_t ws_size,
                              hipStream_t stream) {
    const float* x      = (const float*)d_in[0];
    const float* ai     = (const float*)d_in[1];
    const float* ao     = (const float*)d_in[2];
    const float* a      = (const float*)d_in[3];
    const float* bi     = (const float*)d_in[4];
    const float* bo     = (const float*)d_in[5];
    const float* b      = (const float*)d_in[6];
    const float* ci     = (const float*)d_in[7];
    const float* co     = (const float*)d_in[8];
    const float* c      = (const float*)d_in[9];
    const float* bias_i = (const float*)d_in[10];
    const float* bias   = (const float*)d_in[11];
    float* out = (float*)d_out;

    const size_t elems = (size_t)B_ * W_ * LL;
    __hip_bfloat16* hA = (__hip_bfloat16*)d_ws;
    __hip_bfloat16* hB = hA + elems;

    dim3 grid(B_ * 256), blk(256);
    for (int s = 0; s < 2; ++s) {
        float scale = s ? -1.0f : 1.0f;
        kern_first<<<grid, blk, 0, stream>>>(x, scale, ci, bi, ai, bias_i, hA);
        __hip_bfloat16* cur = hA; __hip_bfloat16* nxt = hB;
        for (int k = 0; k < DEPTH_; ++k) {
            kern_mid<<<grid, blk, 0, stream>>>(cur, c + k*W_*W_, b + k*W_*W_, a + k*W_*W_,
                                               bias + k*W_, nxt);
            __hip_bfloat16* tmp = cur; cur = nxt; nxt = tmp;
        }
        kern_last<<<grid, blk, 0, stream>>>(cur, co, bo, ao, out, s);
    }
}

// Round 4
// 1170.193 us; speedup vs baseline: 3.4114x; 1.2016x over previous
//
#include <hip/hip_runtime.h>
#include <hip/hip_bf16.h>

#define B_ 32
#define L_ 256
#define W_ 32
#define DEPTH_ 4
#define TILE 16
#define HALO 18
#define FPAD 36          // feature channel stride (shorts): 72B, 8B-aligned frags
#define RSTRIDE 20       // tile row stride in shorts: [pad][lh][main0..15][rh][pad]
#define CSTRIDE 362      // tile channel stride in shorts = 181 words (odd -> bank-spread)
#define LL (L_*L_)

typedef float  floatx4 __attribute__((ext_vector_type(4)));
typedef short  shortx2 __attribute__((ext_vector_type(2)));
typedef short  shortx4 __attribute__((ext_vector_type(4)));
typedef short  shortx8 __attribute__((ext_vector_type(8)));

// ---- fast GELU: tanh form, hw exp2/rcp. |err| vs exact erf ~4e-4 rel, << bf16 eps ----
__device__ __forceinline__ float gelu_fast(float x) {
    float x2 = x * x;
    float inner = fmaf(0.044715f * x2, x, x);            // x + 0.044715 x^3
    float y = 0.7978845608028654f * inner;
    float e = __builtin_amdgcn_exp2f(2.8853900817779268f * fabsf(y));  // exp(2|y|)
    float r = __builtin_amdgcn_rcpf(1.0f + e);
    float t = fmaf(-2.0f, r, 1.0f);                      // tanh(|y|)
    t = copysignf(t, x);
    return 0.5f * x * (1.0f + t);
}

// ---- packed f32x2 -> bf16x2 (RNE) ----
#if __has_builtin(__builtin_amdgcn_cvt_pk_bf16_f32)
__device__ __forceinline__ unsigned pack_bf2(float a, float b) {
    auto v = __builtin_amdgcn_cvt_pk_bf16_f32(a, b);
    return __builtin_bit_cast(unsigned, v);
}
#else
__device__ __forceinline__ unsigned pack_bf2(float a, float b) {
    unsigned ua = __float_as_uint(a);
    unsigned ub = __float_as_uint(b);
    ua += 0x7fffu + ((ua >> 16) & 1u);
    ub += 0x7fffu + ((ub >> 16) & 1u);
    return (ua >> 16) | (ub & 0xffff0000u);
}
#endif
__device__ __forceinline__ unsigned short f2bf_fast(float v) {
    return (unsigned short)(pack_bf2(v, v) & 0xffffu);
}
__device__ __forceinline__ unsigned short f2bf(float v) {
    __hip_bfloat16 h = __float2bfloat16(v);
    return __builtin_bit_cast(unsigned short, h);
}
__device__ __forceinline__ float bf2f(unsigned short u) {
    __hip_bfloat16 h = __builtin_bit_cast(__hip_bfloat16, u);
    return __bfloat162float(h);
}
__device__ __forceinline__ float hi16(unsigned r) { return __uint_as_float(r & 0xffff0000u); }
__device__ __forceinline__ float lo16(unsigned r) { return __uint_as_float(r << 16); }

// window shorts e..e+7 in r0..r3; logical window = shorts e+1..e+6
__device__ __forceinline__ void unpack6(unsigned r0, unsigned r1, unsigned r2, unsigned r3, float* w) {
    w[0] = hi16(r0);
    w[1] = lo16(r1); w[2] = hi16(r1);
    w[3] = lo16(r2); w[4] = hi16(r2);
    w[5] = lo16(r3);
}

// XCD-aware swizzle: contiguous logical range per XCD for L2 line sharing
__device__ __forceinline__ int swizzle_blk(int p) {
    return (p & 7) * 1024 + (p >> 3);
}

// ---------------- first layer: 1 channel -> 32 channels ----------------
__global__ __launch_bounds__(256) void kern_first(
        const float* __restrict__ x, float scale,
        const float* __restrict__ ci, const float* __restrict__ bi,
        const float* __restrict__ ai, const float* __restrict__ bias_i,
        __hip_bfloat16* __restrict__ hout) {
    __shared__ float tile[HALO*HALO];
    __shared__ float wC[W_], wB[W_], wA[W_], bs[W_];
    int blk = swizzle_blk(blockIdx.x);
    int b = blk >> 8;
    int t = blk & 255;
    int x0 = (t >> 4) * TILE;
    int y0 = (t & 15) * TILE;
    int tid = threadIdx.x;
    if (tid < W_) { wC[tid] = ci[tid]; wB[tid] = bi[tid]; wA[tid] = ai[tid]; bs[tid] = bias_i[tid]; }
    const float* xb = x + (size_t)b * LL;
    for (int idx = tid; idx < HALO*HALO; idx += 256) {
        int dy = idx / HALO, dx = idx % HALO;
        int gx = (x0 + dy - 1) & (L_ - 1);
        int gy = (y0 + dx - 1) & (L_ - 1);
        tile[idx] = scale * xb[gx * L_ + gy];
    }
    __syncthreads();
    int dx = tid & 15, dy = tid >> 4;
    const float* c0 = &tile[dy * HALO + dx];
    float ctr = c0[HALO + 1];
    float nb  = c0[1] + c0[2*HALO+1] + c0[HALO] + c0[HALO+2];
    float dg  = c0[0] + c0[2] + c0[2*HALO] + c0[2*HALO+2];
    unsigned short* outp = (unsigned short*)hout;
    size_t base = (size_t)b * W_ * LL + (size_t)(x0+dy) * L_ + (y0+dx);
    #pragma unroll
    for (int o = 0; o < W_; ++o) {
        float y = wC[o]*ctr + wB[o]*nb + wA[o]*dg + bs[o];
        outp[base + (size_t)o * LL] = f2bf_fast(gelu_fast(y));
    }
}

// ---------------- staging helper: one (channel,row) job ----------------
__device__ __forceinline__ void stage_row(unsigned short* tile_s, const unsigned short* hb,
                                          int j, int x0, int y0) {
    int i  = j & 31;
    int dy = j >> 5;
    int gx = (x0 + dy - 1) & (L_ - 1);
    const unsigned short* src = hb + (size_t)i * LL + (size_t)gx * L_;
    shortx8 m0 = *(const shortx8*)(src + y0);
    shortx8 m1 = *(const shortx8*)(src + y0 + 8);
    unsigned short lh = src[(y0 - 1) & (L_ - 1)];
    unsigned short rh = src[(y0 + 16) & (L_ - 1)];
    unsigned short* dst = tile_s + i * CSTRIDE + dy * RSTRIDE;
    shortx2* dp = (shortx2*)(dst + 2);
    const shortx2* p0 = (const shortx2*)&m0;
    const shortx2* p1 = (const shortx2*)&m1;
    dp[0] = p0[0]; dp[1] = p0[1]; dp[2] = p0[2]; dp[3] = p0[3];
    dp[4] = p1[0]; dp[5] = p1[1]; dp[6] = p1[2]; dp[7] = p1[3];
    dst[1]  = lh;
    dst[18] = rh;
}

// ---------------- middle layer: 32 -> 32 channels, MFMA ----------------
__global__ __launch_bounds__(256, 4) void kern_mid(
        const __hip_bfloat16* __restrict__ hin,
        const float* __restrict__ wc, const float* __restrict__ wb,
        const float* __restrict__ wa, const float* __restrict__ bias,
        __hip_bfloat16* __restrict__ hout) {
    __shared__ unsigned short tile_s[W_ * CSTRIDE];      // 23168 B
    __shared__ unsigned short feat[3 * 64 * FPAD];       // 13824 B (36992 -> 4 blocks/CU)

    const int tid = threadIdx.x;
    const int blk = swizzle_blk(blockIdx.x);
    const int b  = blk >> 8;
    const int t  = blk & 255;
    const int x0 = (t >> 4) * TILE;
    const int y0 = (t & 15) * TILE;

    const unsigned short* hb = (const unsigned short*)hin + (size_t)b * W_ * LL;

    stage_row(tile_s, hb, tid,       x0, y0);
    stage_row(tile_s, hb, tid + 256, x0, y0);
    if (tid < 64) stage_row(tile_s, hb, tid + 512, x0, y0);

    // ---- A fragments (weights bf16 hi/lo) + bias ----
    const int lane = tid & 63;
    const int wv   = tid >> 6;
    const int m    = lane & 15;
    const int q    = lane >> 4;
    const float* wmat[3] = { wc, wb, wa };
    shortx8 afrag[3][2][2];
    #pragma unroll
    for (int f = 0; f < 3; ++f)
      #pragma unroll
      for (int h = 0; h < 2; ++h) {
        const float* row = wmat[f] + (h*16 + m) * W_ + q*8;
        shortx8 hi, lo;
        #pragma unroll
        for (int j = 0; j < 8; ++j) {
            float v = row[j];
            unsigned short hb16 = f2bf(v);
            hi[j] = (short)hb16;
            lo[j] = (short)f2bf(v - bf2f(hb16));
        }
        afrag[f][h][0] = hi;
        afrag[f][h][1] = lo;
      }
    float bias_v[2][4];
    #pragma unroll
    for (int h = 0; h < 2; ++h)
      #pragma unroll
      for (int r = 0; r < 4; ++r)
        bias_v[h][r] = bias[h*16 + q*4 + r];

    __syncthreads();

    const unsigned* tw = (const unsigned*)tile_s;
    unsigned* feat32 = (unsigned*)feat;

    const int cp = tid & 15;         // channel pair: channels 2cp, 2cp+1
    const int sp = tid >> 4;         // 16 segments
    const int rr = sp >> 2;
    const int qy = sp & 3;
    unsigned short* outp = (unsigned short*)hout;

    for (int p = 0; p < 4; ++p) {
        // ---- feature build: this thread does channels 2cp,2cp+1 for 4 sites ----
        {
            int row = p*4 + rr;
            int wb0 = (2*cp) * 181 + row * 10 + qy * 2;
            float v0[3][4];
            {
                float u[6], c[6], d[6];
                unpack6(tw[wb0],    tw[wb0+1],  tw[wb0+2],  tw[wb0+3],  u);
                unpack6(tw[wb0+10], tw[wb0+11], tw[wb0+12], tw[wb0+13], c);
                unpack6(tw[wb0+20], tw[wb0+21], tw[wb0+22], tw[wb0+23], d);
                #pragma unroll
                for (int j = 0; j < 4; ++j) {
                    v0[0][j] = c[j+1];
                    v0[1][j] = u[j+1] + d[j+1] + c[j] + c[j+2];
                    v0[2][j] = u[j] + u[j+2] + d[j] + d[j+2];
                }
            }
            {
                int wb1 = wb0 + 181;
                float u[6], c[6], d[6];
                unpack6(tw[wb1],    tw[wb1+1],  tw[wb1+2],  tw[wb1+3],  u);
                unpack6(tw[wb1+10], tw[wb1+11], tw[wb1+12], tw[wb1+13], c);
                unpack6(tw[wb1+20], tw[wb1+21], tw[wb1+22], tw[wb1+23], d);
                int sbase = rr*16 + qy*4;
                #pragma unroll
                for (int j = 0; j < 4; ++j) {
                    int s = sbase + j;
                    float ctr = c[j+1];
                    float nb  = u[j+1] + d[j+1] + c[j] + c[j+2];
                    float dg  = u[j] + u[j+2] + d[j] + d[j+2];
                    feat32[(0*64 + s)*18 + cp] = pack_bf2(v0[0][j], ctr);
                    feat32[(1*64 + s)*18 + cp] = pack_bf2(v0[1][j], nb);
                    feat32[(2*64 + s)*18 + cp] = pack_bf2(v0[2][j], dg);
                }
            }
        }
        __syncthreads();

        // ---- MFMA: wave wv -> site-row wv, sites s = wv*16 + m ----
        int s = wv*16 + m;
        floatx4 acc[2] = {{0.f,0.f,0.f,0.f},{0.f,0.f,0.f,0.f}};
        #pragma unroll
        for (int f = 0; f < 3; ++f) {
            const unsigned short* fb = &feat[(f*64 + s)*FPAD + q*8];
            union { shortx8 v8; shortx4 v4[2]; } uu;
            uu.v4[0] = *(const shortx4*)(fb);
            uu.v4[1] = *(const shortx4*)(fb+4);
            #pragma unroll
            for (int h = 0; h < 2; ++h) {
                acc[h] = __builtin_amdgcn_mfma_f32_16x16x32_bf16(afrag[f][h][1], uu.v8, acc[h], 0, 0, 0);
                acc[h] = __builtin_amdgcn_mfma_f32_16x16x32_bf16(afrag[f][h][0], uu.v8, acc[h], 0, 0, 0);
            }
        }
        __syncthreads();

        // ---- epilogue: C/D col=lane&15 (site y), row=q*4+r ----
        int gx = x0 + p*4 + wv;
        int gy = y0 + m;
        #pragma unroll
        for (int h = 0; h < 2; ++h)
          #pragma unroll
          for (int r = 0; r < 4; ++r) {
            int oc = h*16 + q*4 + r;
            float v = gelu_fast(acc[h][r] + bias_v[h][r]);
            outp[((size_t)b*W_ + oc)*LL + (size_t)gx*L_ + gy] = f2bf_fast(v);
          }
    }
}

// ---------------- last layer: 32 -> 1 channel, antisym accumulate ----------------
__global__ __launch_bounds__(256, 4) void kern_last(
        const __hip_bfloat16* __restrict__ hin,
        const float* __restrict__ co, const float* __restrict__ bo,
        const float* __restrict__ ao,
        float* __restrict__ out, int mode) {
    __shared__ unsigned short tile_s[W_ * CSTRIDE];      // 23168 B
    const int tid = threadIdx.x;
    const int blk = swizzle_blk(blockIdx.x);
    const int b  = blk >> 8;
    const int t  = blk & 255;
    const int x0 = (t >> 4) * TILE;
    const int y0 = (t & 15) * TILE;

    const unsigned short* hb = (const unsigned short*)hin + (size_t)b * W_ * LL;
    stage_row(tile_s, hb, tid,       x0, y0);
    stage_row(tile_s, hb, tid + 256, x0, y0);
    if (tid < 64) stage_row(tile_s, hb, tid + 512, x0, y0);

    const int cp = tid & 15;
    const int sp = tid >> 4;
    const int rr = sp >> 2;
    const int qy = sp & 3;
    int i0 = 2*cp;
    float wC0 = co[i0], wC1 = co[i0+1];
    float wB0 = bo[i0], wB1 = bo[i0+1];
    float wA0 = ao[i0], wA1 = ao[i0+1];

    __syncthreads();
    const unsigned* tw = (const unsigned*)tile_s;

    for (int p = 0; p < 4; ++p) {
        int row = p*4 + rr;
        int wb0 = i0 * 181 + row * 10 + qy * 2;
        float ps[4];
        {
            float u[6], c[6], d[6];
            unpack6(tw[wb0],    tw[wb0+1],  tw[wb0+2],  tw[wb0+3],  u);
            unpack6(tw[wb0+10], tw[wb0+11], tw[wb0+12], tw[wb0+13], c);
            unpack6(tw[wb0+20], tw[wb0+21], tw[wb0+22], tw[wb0+23], d);
            #pragma unroll
            for (int j = 0; j < 4; ++j) {
                float ctr = c[j+1];
                float nb  = u[j+1] + d[j+1] + c[j] + c[j+2];
                float dg  = u[j] + u[j+2] + d[j] + d[j+2];
                ps[j] = wC0*ctr + wB0*nb + wA0*dg;
            }
        }
        {
            int wb1 = wb0 + 181;
            float u[6], c[6], d[6];
            unpack6(tw[wb1],    tw[wb1+1],  tw[wb1+2],  tw[wb1+3],  u);
            unpack6(tw[wb1+10], tw[wb1+11], tw[wb1+12], tw[wb1+13], c);
            unpack6(tw[wb1+20], tw[wb1+21], tw[wb1+22], tw[wb1+23], d);
            #pragma unroll
            for (int j = 0; j < 4; ++j) {
                float ctr = c[j+1];
                float nb  = u[j+1] + d[j+1] + c[j] + c[j+2];
                float dg  = u[j] + u[j+2] + d[j] + d[j+2];
                ps[j] += wC1*ctr + wB1*nb + wA1*dg;
            }
        }
        // 16-lane butterfly over channel-pairs
        #pragma unroll
        for (int mask = 1; mask < 16; mask <<= 1) {
            #pragma unroll
            for (int j = 0; j < 4; ++j)
                ps[j] += __shfl_xor(ps[j], mask);
        }
        if (cp < 4) {
            int col = qy*4 + cp;
            size_t oidx = (size_t)b * LL + (size_t)(x0 + row) * L_ + (y0 + col);
            float v = 0.5f * ps[cp];
            if (mode == 0) out[oidx] = v;
            else           out[oidx] = out[oidx] - v;
        }
    }
}

extern "C" void kernel_launch(void* const* d_in, const int* in_sizes, int n_in,
                              void* d_out, int out_size, void* d_ws, size_t ws_size,
                              hipStream_t stream) {
    const float* x      = (const float*)d_in[0];
    const float* ai     = (const float*)d_in[1];
    const float* ao     = (const float*)d_in[2];
    const float* a      = (const float*)d_in[3];
    const float* bi     = (const float*)d_in[4];
    const float* bo     = (const float*)d_in[5];
    const float* b      = (const float*)d_in[6];
    const float* ci     = (const float*)d_in[7];
    const float* co     = (const float*)d_in[8];
    const float* c      = (const float*)d_in[9];
    const float* bias_i = (const float*)d_in[10];
    const float* bias   = (const float*)d_in[11];
    float* out = (float*)d_out;

    const size_t elems = (size_t)B_ * W_ * LL;
    __hip_bfloat16* hA = (__hip_bfloat16*)d_ws;
    __hip_bfloat16* hB = hA + elems;

    dim3 grid(B_ * 256), blk(256);
    for (int s = 0; s < 2; ++s) {
        float scale = s ? -1.0f : 1.0f;
        kern_first<<<grid, blk, 0, stream>>>(x, scale, ci, bi, ai, bias_i, hA);
        __hip_bfloat16* cur = hA; __hip_bfloat16* nxt = hB;
        for (int k = 0; k < DEPTH_; ++k) {
            kern_mid<<<grid, blk, 0, stream>>>(cur, c + k*W_*W_, b + k*W_*W_, a + k*W_*W_,
                                               bias + k*W_, nxt);
            __hip_bfloat16* tmp = cur; cur = nxt; nxt = tmp;
        }
        kern_last<<<grid, blk, 0, stream>>>(cur, co, bo, ao, out, s);
    }
}